// Round 1
// baseline (1870.431 us; speedup 1.0000x reference)
//
#include <hip/hip_runtime.h>
#include <hip/hip_bf16.h>

// Problem constants
#define NROWS 16384      // B*C = 32*512
#define DDIM  256        // H*W
#define KEMB  8192
#define DECAYF 0.99f
#define ONE_MINUS_DECAY 0.01f
#define EPSF 1e-5f

// Output layout (all float32, concatenated in return order)
#define O_QST   0
#define O_LOSS  4194304
#define O_IDX   4194305
#define O_EMB   4210689
#define O_ECS   6307841
#define O_EES   6316033

// Workspace layout (floats)
#define WS_NORMS 0          // 8192
#define WS_PDIST 8192       // 16384*4
#define WS_PIDX  73728      // 16384*4 (int)
#define WS_IDX   139264     // 16384 (int)
#define WS_SCAL  155648     // [0]=loss_sum, [1]=n_tot

// ---------------- K1: embedding norms ----------------
__global__ __launch_bounds__(256) void norms_kernel(const float* __restrict__ emb,
                                                    float* __restrict__ enorm) {
    const int k = blockIdx.x * 4 + (threadIdx.x >> 6);
    const int lane = threadIdx.x & 63;
    float4 v = *(const float4*)&emb[k * DDIM + lane * 4];
    float s = v.x * v.x + v.y * v.y + v.z * v.z + v.w * v.w;
    for (int o = 32; o; o >>= 1) s += __shfl_down(s, o);
    if (lane == 0) enorm[k] = s;
}

// ---------------- K2: init outputs + zero scalars ----------------
__global__ __launch_bounds__(256) void init_kernel(const float* __restrict__ ecs_in,
                                                   const float* __restrict__ ees_in,
                                                   float* __restrict__ o_ecs,
                                                   float* __restrict__ o_ees,
                                                   float* __restrict__ scal) {
    const int i = blockIdx.x * 256 + threadIdx.x;
    o_ees[i] = DECAYF * ees_in[i];
    if (i < KEMB) o_ecs[i] = DECAYF * ecs_in[i];
    if (i < 2) scal[i] = 0.0f;
}

// ---------------- K3: fused distance GEMM + argmin (partial per k-group) ----
#define TM 64
#define TN 64
#define DK 16
#define KGROUPS 4
#define KGROUP (KEMB / KGROUPS)

__global__ __launch_bounds__(256) void argmin_gemm(const float* __restrict__ z,
                                                   const float* __restrict__ emb,
                                                   const float* __restrict__ enorm,
                                                   float* __restrict__ pdist,
                                                   int* __restrict__ pidx) {
    __shared__ float As[TM][DK + 4];   // pitch 20 floats: 16B-aligned rows, no 16-way bank conflict
    __shared__ float Bs[TN][DK + 4];
    __shared__ float rd[TM][16];
    __shared__ int   ri[TM][16];

    const int tid = threadIdx.x;
    const int tx = tid & 15, ty = tid >> 4;
    const int row0 = blockIdx.x * TM;
    const int kbase0 = blockIdx.y * KGROUP;

    const int lr = tid >> 2;          // load row 0..63
    const int lc = (tid & 3) * 4;     // load col 0,4,8,12

    float bestd[4];
    int bestk[4];
#pragma unroll
    for (int i = 0; i < 4; i++) { bestd[i] = 3.4e38f; bestk[i] = 0; }

    for (int chunk = 0; chunk < KGROUP / TN; ++chunk) {
        const int kbase = kbase0 + chunk * TN;
        float acc[4][4] = {};
        for (int dstep = 0; dstep < DDIM; dstep += DK) {
            const float4 av = *(const float4*)&z[(row0 + lr) * DDIM + dstep + lc];
            const float4 bv = *(const float4*)&emb[(kbase + lr) * DDIM + dstep + lc];
            __syncthreads();                       // protect previous iter's reads
            *(float4*)&As[lr][lc] = av;
            *(float4*)&Bs[lr][lc] = bv;
            __syncthreads();
#pragma unroll
            for (int dd = 0; dd < DK; dd += 4) {
                float4 a[4], b[4];
#pragma unroll
                for (int i = 0; i < 4; i++) a[i] = *(const float4*)&As[ty * 4 + i][dd];
#pragma unroll
                for (int j = 0; j < 4; j++) b[j] = *(const float4*)&Bs[tx * 4 + j][dd];
#pragma unroll
                for (int i = 0; i < 4; i++)
#pragma unroll
                    for (int j = 0; j < 4; j++)
                        acc[i][j] += a[i].x * b[j].x + a[i].y * b[j].y +
                                     a[i].z * b[j].z + a[i].w * b[j].w;
            }
        }
        // epilogue for this 64-col chunk: score = ||e||^2 - 2 x.e, running argmin
#pragma unroll
        for (int j = 0; j < 4; j++) {
            const int k = kbase + tx * 4 + j;
            const float en = enorm[k];
#pragma unroll
            for (int i = 0; i < 4; i++) {
                const float s = en - 2.0f * acc[i][j];
                if (s < bestd[i]) { bestd[i] = s; bestk[i] = k; }  // k ascending -> numpy tie-break
            }
        }
    }

    __syncthreads();
#pragma unroll
    for (int i = 0; i < 4; i++) { rd[ty * 4 + i][tx] = bestd[i]; ri[ty * 4 + i][tx] = bestk[i]; }
    __syncthreads();
    if (tid < TM) {
        float bd = rd[tid][0];
        int bk = ri[tid][0];
        for (int t = 1; t < 16; t++) {
            const float d = rd[tid][t];
            const int k2 = ri[tid][t];
            if (d < bd || (d == bd && k2 < bk)) { bd = d; bk = k2; }
        }
        const int row = row0 + tid;
        pdist[row * KGROUPS + blockIdx.y] = bd;
        pidx[row * KGROUPS + blockIdx.y] = bk;
    }
}

// ---------------- K4: merge k-group partials ----------------
__global__ __launch_bounds__(256) void merge_kernel(const float* __restrict__ pdist,
                                                    const int* __restrict__ pidx,
                                                    int* __restrict__ idx_ws,
                                                    float* __restrict__ o_idx) {
    const int n = blockIdx.x * 256 + threadIdx.x;
    float bd = pdist[n * KGROUPS];
    int bk = pidx[n * KGROUPS];
    for (int g = 1; g < KGROUPS; ++g) {
        const float d = pdist[n * KGROUPS + g];
        const int k = pidx[n * KGROUPS + g];
        if (d < bd || (d == bd && k < bk)) { bd = d; bk = k; }
    }
    idx_ws[n] = bk;
    o_idx[n] = (float)bk;
}

// ---------------- K5: quantize + commit-loss + EMA stats ----------------
__global__ __launch_bounds__(256) void quant_stats(const float* __restrict__ z,
                                                   const float* __restrict__ emb,
                                                   const int* __restrict__ idx_ws,
                                                   float* __restrict__ o_qst,
                                                   float* __restrict__ o_ecs,
                                                   float* __restrict__ o_ees,
                                                   float* __restrict__ scal) {
    const int n = (blockIdx.x * 256 + threadIdx.x) >> 6;   // one wave per row
    const int lane = threadIdx.x & 63;
    const int k = idx_ws[n];
    const int d0 = lane * 4;
    const float4 zv = *(const float4*)&z[n * DDIM + d0];
    const float4 ev = *(const float4*)&emb[k * DDIM + d0];
    // q_st = z + (quantized - z), computed exactly as the reference rounds it
    const float dx = ev.x - zv.x, dy = ev.y - zv.y, dz2 = ev.z - zv.z, dw = ev.w - zv.w;
    float4 q;
    q.x = zv.x + dx; q.y = zv.y + dy; q.z = zv.z + dz2; q.w = zv.w + dw;
    *(float4*)&o_qst[n * DDIM + d0] = q;
    float p = dx * dx + dy * dy + dz2 * dz2 + dw * dw;
    for (int o = 32; o; o >>= 1) p += __shfl_down(p, o);
    if (lane == 0) {
        atomicAdd(&scal[0], p);
        atomicAdd(&o_ecs[k], ONE_MINUS_DECAY);
    }
    atomicAdd(&o_ees[k * DDIM + d0 + 0], ONE_MINUS_DECAY * zv.x);
    atomicAdd(&o_ees[k * DDIM + d0 + 1], ONE_MINUS_DECAY * zv.y);
    atomicAdd(&o_ees[k * DDIM + d0 + 2], ONE_MINUS_DECAY * zv.z);
    atomicAdd(&o_ees[k * DDIM + d0 + 3], ONE_MINUS_DECAY * zv.w);
}

// ---------------- K6a: n_tot = sum(new_ecs) ----------------
__global__ __launch_bounds__(256) void ntot_kernel(const float* __restrict__ o_ecs,
                                                   float* __restrict__ scal) {
    const int i = blockIdx.x * 256 + threadIdx.x;
    float v = o_ecs[i];
    for (int o = 32; o; o >>= 1) v += __shfl_down(v, o);
    __shared__ float s[4];
    if ((threadIdx.x & 63) == 0) s[threadIdx.x >> 6] = v;
    __syncthreads();
    if (threadIdx.x == 0) atomicAdd(&scal[1], s[0] + s[1] + s[2] + s[3]);
}

// ---------------- K6b: new_embedding + loss scalar ----------------
__global__ __launch_bounds__(256) void finalize_kernel(const float* __restrict__ o_ecs,
                                                       const float* __restrict__ o_ees,
                                                       const float* __restrict__ scal,
                                                       float* __restrict__ o_emb,
                                                       float* __restrict__ o_loss) {
    const int k = blockIdx.x;
    const int d = threadIdx.x;
    const float ntot = scal[1];
    const float ecs = o_ecs[k];
    const float sm = (ecs + EPSF) / (ntot + (float)KEMB * EPSF) * ntot;
    o_emb[k * DDIM + d] = o_ees[k * DDIM + d] / sm;
    if (k == 0 && d == 0) o_loss[0] = 0.25f * scal[0] / (float)(NROWS * DDIM);
}

extern "C" void kernel_launch(void* const* d_in, const int* in_sizes, int n_in,
                              void* d_out, int out_size, void* d_ws, size_t ws_size,
                              hipStream_t stream) {
    const float* z   = (const float*)d_in[0];
    const float* emb = (const float*)d_in[1];
    const float* ecs = (const float*)d_in[2];
    const float* ees = (const float*)d_in[3];

    float* out = (float*)d_out;
    float* ws  = (float*)d_ws;

    float* enorm = ws + WS_NORMS;
    float* pdist = ws + WS_PDIST;
    int*   pidx  = (int*)(ws + WS_PIDX);
    int*   idxw  = (int*)(ws + WS_IDX);
    float* scal  = ws + WS_SCAL;

    norms_kernel<<<KEMB / 4, 256, 0, stream>>>(emb, enorm);
    init_kernel<<<(KEMB * DDIM) / 256, 256, 0, stream>>>(ecs, ees, out + O_ECS, out + O_EES, scal);
    argmin_gemm<<<dim3(NROWS / TM, KGROUPS), 256, 0, stream>>>(z, emb, enorm, pdist, pidx);
    merge_kernel<<<NROWS / 256, 256, 0, stream>>>(pdist, pidx, idxw, out + O_IDX);
    quant_stats<<<(NROWS * 64) / 256, 256, 0, stream>>>(z, emb, idxw, out + O_QST,
                                                        out + O_ECS, out + O_EES, scal);
    ntot_kernel<<<KEMB / 256, 256, 0, stream>>>(out + O_ECS, scal);
    finalize_kernel<<<KEMB, DDIM, 0, stream>>>(out + O_ECS, out + O_EES, scal,
                                               out + O_EMB, out + O_LOSS);
}

// Round 2
// 645.111 us; speedup vs baseline: 2.8994x; 2.8994x over previous
//
#include <hip/hip_runtime.h>
#include <hip/hip_bf16.h>

// Problem constants
#define NROWS 16384      // B*C = 32*512
#define DDIM  256        // H*W
#define KEMB  8192
#define DECAYF 0.99f
#define ONE_MINUS_DECAY 0.01f
#define EPSF 1e-5f

// Output layout (all float32, concatenated in return order)
#define O_QST   0
#define O_LOSS  4194304
#define O_IDX   4194305
#define O_EMB   4210689
#define O_ECS   6307841
#define O_EES   6316033

// Workspace layout (float offsets)
#define WS_NORMS 0          // 8192 floats
#define WS_KEY   8192       // 16384 x u64 = 32768 floats (8B aligned: byte 32768)
#define WS_IDX   40960      // 16384 ints
#define WS_SCAL  57344      // [0]=loss_sum, [1]=n_tot

typedef __attribute__((ext_vector_type(8))) short short8;
typedef __attribute__((ext_vector_type(4))) float f32x4;

// fp32 -> bf16 (RNE) as raw ushort, and back
static __device__ __forceinline__ unsigned short f2bf(float x) {
    unsigned int u = __float_as_uint(x);
    return (unsigned short)((u + 0x7fffu + ((u >> 16) & 1u)) >> 16);
}
static __device__ __forceinline__ float bf2f(unsigned short h) {
    return __uint_as_float(((unsigned int)h) << 16);
}

// ---------------- K1: embedding norms (exact fp32) ----------------
__global__ __launch_bounds__(256) void norms_kernel(const float* __restrict__ emb,
                                                    float* __restrict__ enorm) {
    const int k = blockIdx.x * 4 + (threadIdx.x >> 6);
    const int lane = threadIdx.x & 63;
    float4 v = *(const float4*)&emb[k * DDIM + lane * 4];
    float s = v.x * v.x + v.y * v.y + v.z * v.z + v.w * v.w;
    for (int o = 32; o; o >>= 1) s += __shfl_down(s, o);
    if (lane == 0) enorm[k] = s;
}

// ---------------- K2: init outputs + keys + scalars ----------------
__global__ __launch_bounds__(256) void init_kernel(const float* __restrict__ ecs_in,
                                                   const float* __restrict__ ees_in,
                                                   float* __restrict__ o_ecs,
                                                   float* __restrict__ o_ees,
                                                   unsigned long long* __restrict__ key64,
                                                   float* __restrict__ scal) {
    const int i = blockIdx.x * 256 + threadIdx.x;
    o_ees[i] = DECAYF * ees_in[i];
    if (i < KEMB) o_ecs[i] = DECAYF * ecs_in[i];
    if (i < NROWS) key64[i] = ~0ull;
    if (i < 2) scal[i] = 0.0f;
}

// ---------------- K3: bf16x3 MFMA distance GEMM + fused argmin ----------------
// Block: 128 rows x 128 cols, 4 waves (2x2 of 64x64), K-loop over D in BK=32.
// acc += Ahi*Bhi + Alo*Bhi + Ahi*Blo  (bf16x3 ~ fp32 dot)
__global__ __launch_bounds__(256) void argmin_mfma(const float* __restrict__ z,
                                                   const float* __restrict__ emb,
                                                   const float* __restrict__ enorm,
                                                   unsigned long long* __restrict__ key64) {
    // pitch 40 ushorts (80 B): rows 16B-aligned, frag reads perfectly bank-balanced
    __shared__ unsigned short Ah[128][40];
    __shared__ unsigned short Al[128][40];
    __shared__ unsigned short Bh[128][40];
    __shared__ unsigned short Bl[128][40];

    const int tid = threadIdx.x;
    const int lane = tid & 63;
    const int wid = tid >> 6;
    const int wm = wid >> 1, wn = wid & 1;
    const int tx = lane & 15, quad = lane >> 4;

    const int row0 = blockIdx.x * 128;
    const int col0 = blockIdx.y * 128;

    // staging assignment: thread t loads row t>>1, 16 consecutive floats at (t&1)*16
    const int srow = tid >> 1;
    const int sc0 = (tid & 1) * 16;

    f32x4 acc[4][4];
#pragma unroll
    for (int i = 0; i < 4; i++)
#pragma unroll
        for (int j = 0; j < 4; j++) acc[i][j] = (f32x4){0.f, 0.f, 0.f, 0.f};

    for (int dstep = 0; dstep < DDIM; dstep += 32) {
        float4 av[4], bv[4];
        const float* ap = &z[(row0 + srow) * DDIM + dstep + sc0];
        const float* bp = &emb[(col0 + srow) * DDIM + dstep + sc0];
#pragma unroll
        for (int i = 0; i < 4; i++) {
            av[i] = *(const float4*)(ap + 4 * i);
            bv[i] = *(const float4*)(bp + 4 * i);
        }
        __syncthreads();   // previous iter's frag reads complete before overwrite
        {
            short8 vh0, vl0, vh1, vl1;
#pragma unroll
            for (int i = 0; i < 2; i++)
#pragma unroll
                for (int j = 0; j < 4; j++) {
                    float x = ((const float*)&av[i])[j];
                    unsigned short hh = f2bf(x);
                    vh0[i * 4 + j] = (short)hh;
                    vl0[i * 4 + j] = (short)f2bf(x - bf2f(hh));
                }
#pragma unroll
            for (int i = 0; i < 2; i++)
#pragma unroll
                for (int j = 0; j < 4; j++) {
                    float x = ((const float*)&av[i + 2])[j];
                    unsigned short hh = f2bf(x);
                    vh1[i * 4 + j] = (short)hh;
                    vl1[i * 4 + j] = (short)f2bf(x - bf2f(hh));
                }
            *(short8*)&Ah[srow][sc0] = vh0;
            *(short8*)&Ah[srow][sc0 + 8] = vh1;
            *(short8*)&Al[srow][sc0] = vl0;
            *(short8*)&Al[srow][sc0 + 8] = vl1;
#pragma unroll
            for (int i = 0; i < 2; i++)
#pragma unroll
                for (int j = 0; j < 4; j++) {
                    float x = ((const float*)&bv[i])[j];
                    unsigned short hh = f2bf(x);
                    vh0[i * 4 + j] = (short)hh;
                    vl0[i * 4 + j] = (short)f2bf(x - bf2f(hh));
                }
#pragma unroll
            for (int i = 0; i < 2; i++)
#pragma unroll
                for (int j = 0; j < 4; j++) {
                    float x = ((const float*)&bv[i + 2])[j];
                    unsigned short hh = f2bf(x);
                    vh1[i * 4 + j] = (short)hh;
                    vl1[i * 4 + j] = (short)f2bf(x - bf2f(hh));
                }
            *(short8*)&Bh[srow][sc0] = vh0;
            *(short8*)&Bh[srow][sc0 + 8] = vh1;
            *(short8*)&Bl[srow][sc0] = vl0;
            *(short8*)&Bl[srow][sc0 + 8] = vl1;
        }
        __syncthreads();

        short8 aH[4], aL[4], bH[4], bL[4];
        const int ar = wm * 64 + tx;
        const int br = wn * 64 + tx;
#pragma unroll
        for (int mi = 0; mi < 4; mi++) {
            aH[mi] = *(const short8*)&Ah[ar + mi * 16][quad * 8];
            aL[mi] = *(const short8*)&Al[ar + mi * 16][quad * 8];
        }
#pragma unroll
        for (int nj = 0; nj < 4; nj++) {
            bH[nj] = *(const short8*)&Bh[br + nj * 16][quad * 8];
            bL[nj] = *(const short8*)&Bl[br + nj * 16][quad * 8];
        }
#pragma unroll
        for (int mi = 0; mi < 4; mi++)
#pragma unroll
            for (int nj = 0; nj < 4; nj++) {
                acc[mi][nj] = __builtin_amdgcn_mfma_f32_16x16x32_bf16(aH[mi], bH[nj], acc[mi][nj], 0, 0, 0);
                acc[mi][nj] = __builtin_amdgcn_mfma_f32_16x16x32_bf16(aL[mi], bH[nj], acc[mi][nj], 0, 0, 0);
                acc[mi][nj] = __builtin_amdgcn_mfma_f32_16x16x32_bf16(aH[mi], bL[nj], acc[mi][nj], 0, 0, 0);
            }
    }

    // epilogue: dist = ||e||^2 - 2 x.e ; fused argmin with k-ascending tie-break.
    // C/D layout: col = lane&15 (+nj*16), row = quad*4 + reg (+mi*16)  [m89-verified]
    float en[4];
    int colv[4];
#pragma unroll
    for (int nj = 0; nj < 4; nj++) {
        colv[nj] = col0 + wn * 64 + nj * 16 + tx;
        en[nj] = enorm[colv[nj]];
    }
#pragma unroll
    for (int mi = 0; mi < 4; mi++) {
#pragma unroll
        for (int r = 0; r < 4; r++) {
            unsigned long long best = ~0ull;
#pragma unroll
            for (int nj = 0; nj < 4; nj++) {
                float d = en[nj] - 2.0f * acc[mi][nj][r];
                unsigned int db = __float_as_uint(d);
                db = (db & 0x80000000u) ? ~db : (db | 0x80000000u);
                unsigned long long key = ((unsigned long long)db << 32) | (unsigned int)colv[nj];
                if (key < best) best = key;
            }
#pragma unroll
            for (int m = 1; m < 16; m <<= 1) {
                unsigned long long o = __shfl_xor(best, m);
                if (o < best) best = o;
            }
            if (tx == 0)
                atomicMin(&key64[row0 + wm * 64 + mi * 16 + quad * 4 + r], best);
        }
    }
}

// ---------------- K4: decode keys ----------------
__global__ __launch_bounds__(256) void merge_kernel(const unsigned long long* __restrict__ key64,
                                                    int* __restrict__ idx_ws,
                                                    float* __restrict__ o_idx) {
    const int n = blockIdx.x * 256 + threadIdx.x;
    const int k = (int)(key64[n] & 0xFFFFFFFFull);
    idx_ws[n] = k;
    o_idx[n] = (float)k;
}

// ---------------- K5: quantize + commit-loss + EMA stats ----------------
__global__ __launch_bounds__(256) void quant_stats(const float* __restrict__ z,
                                                   const float* __restrict__ emb,
                                                   const int* __restrict__ idx_ws,
                                                   float* __restrict__ o_qst,
                                                   float* __restrict__ o_ecs,
                                                   float* __restrict__ o_ees,
                                                   float* __restrict__ scal) {
    const int n = (blockIdx.x * 256 + threadIdx.x) >> 6;   // one wave per row
    const int lane = threadIdx.x & 63;
    const int k = idx_ws[n];
    const int d0 = lane * 4;
    const float4 zv = *(const float4*)&z[n * DDIM + d0];
    const float4 ev = *(const float4*)&emb[k * DDIM + d0];
    const float dx = ev.x - zv.x, dy = ev.y - zv.y, dz2 = ev.z - zv.z, dw = ev.w - zv.w;
    float4 q;
    q.x = zv.x + dx; q.y = zv.y + dy; q.z = zv.z + dz2; q.w = zv.w + dw;
    *(float4*)&o_qst[n * DDIM + d0] = q;
    float p = dx * dx + dy * dy + dz2 * dz2 + dw * dw;
    for (int o = 32; o; o >>= 1) p += __shfl_down(p, o);
    if (lane == 0) {
        atomicAdd(&scal[0], p);
        atomicAdd(&o_ecs[k], ONE_MINUS_DECAY);
    }
    atomicAdd(&o_ees[k * DDIM + d0 + 0], ONE_MINUS_DECAY * zv.x);
    atomicAdd(&o_ees[k * DDIM + d0 + 1], ONE_MINUS_DECAY * zv.y);
    atomicAdd(&o_ees[k * DDIM + d0 + 2], ONE_MINUS_DECAY * zv.z);
    atomicAdd(&o_ees[k * DDIM + d0 + 3], ONE_MINUS_DECAY * zv.w);
}

// ---------------- K6a: n_tot = sum(new_ecs) ----------------
__global__ __launch_bounds__(256) void ntot_kernel(const float* __restrict__ o_ecs,
                                                   float* __restrict__ scal) {
    const int i = blockIdx.x * 256 + threadIdx.x;
    float v = o_ecs[i];
    for (int o = 32; o; o >>= 1) v += __shfl_down(v, o);
    __shared__ float s[4];
    if ((threadIdx.x & 63) == 0) s[threadIdx.x >> 6] = v;
    __syncthreads();
    if (threadIdx.x == 0) atomicAdd(&scal[1], s[0] + s[1] + s[2] + s[3]);
}

// ---------------- K6b: new_embedding + loss scalar ----------------
__global__ __launch_bounds__(256) void finalize_kernel(const float* __restrict__ o_ecs,
                                                       const float* __restrict__ o_ees,
                                                       const float* __restrict__ scal,
                                                       float* __restrict__ o_emb,
                                                       float* __restrict__ o_loss) {
    const int k = blockIdx.x;
    const int d = threadIdx.x;
    const float ntot = scal[1];
    const float ecs = o_ecs[k];
    const float sm = (ecs + EPSF) / (ntot + (float)KEMB * EPSF) * ntot;
    o_emb[k * DDIM + d] = o_ees[k * DDIM + d] / sm;
    if (k == 0 && d == 0) o_loss[0] = 0.25f * scal[0] / (float)(NROWS * DDIM);
}

extern "C" void kernel_launch(void* const* d_in, const int* in_sizes, int n_in,
                              void* d_out, int out_size, void* d_ws, size_t ws_size,
                              hipStream_t stream) {
    const float* z   = (const float*)d_in[0];
    const float* emb = (const float*)d_in[1];
    const float* ecs = (const float*)d_in[2];
    const float* ees = (const float*)d_in[3];

    float* out = (float*)d_out;
    float* ws  = (float*)d_ws;

    float* enorm = ws + WS_NORMS;
    unsigned long long* key64 = (unsigned long long*)(ws + WS_KEY);
    int*   idxw  = (int*)(ws + WS_IDX);
    float* scal  = ws + WS_SCAL;

    norms_kernel<<<KEMB / 4, 256, 0, stream>>>(emb, enorm);
    init_kernel<<<(KEMB * DDIM) / 256, 256, 0, stream>>>(ecs, ees, out + O_ECS, out + O_EES, key64, scal);
    argmin_mfma<<<dim3(NROWS / 128, KEMB / 128), 256, 0, stream>>>(z, emb, enorm, key64);
    merge_kernel<<<NROWS / 256, 256, 0, stream>>>(key64, idxw, out + O_IDX);
    quant_stats<<<(NROWS * 64) / 256, 256, 0, stream>>>(z, emb, idxw, out + O_QST,
                                                        out + O_ECS, out + O_EES, scal);
    ntot_kernel<<<KEMB / 256, 256, 0, stream>>>(out + O_ECS, scal);
    finalize_kernel<<<KEMB, DDIM, 0, stream>>>(out + O_ECS, out + O_EES, scal,
                                               out + O_EMB, out + O_LOSS);
}

// Round 3
// 599.659 us; speedup vs baseline: 3.1192x; 1.0758x over previous
//
#include <hip/hip_runtime.h>
#include <hip/hip_bf16.h>

// Problem constants
#define NROWS 16384      // B*C = 32*512
#define DDIM  256        // H*W
#define KEMB  8192
#define DECAYF 0.99f
#define ONE_MINUS_DECAY 0.01f
#define EPSF 1e-5f

// Output layout (all float32, concatenated in return order)
#define O_QST   0
#define O_LOSS  4194304
#define O_IDX   4194305
#define O_EMB   4210689
#define O_ECS   6307841
#define O_EES   6316033

// Workspace layout (float offsets)
#define WS_NORMS 0          // 8192 floats
#define WS_KEY   8192       // 16384 x u64 (8B aligned: byte 32768)
#define WS_SCAL  57344      // [0]=loss_sum, [1]=n_tot

typedef __attribute__((ext_vector_type(8))) short short8;
typedef __attribute__((ext_vector_type(4))) float f32x4;

// fp32 -> bf16 (RNE) as raw ushort, and back
static __device__ __forceinline__ unsigned short f2bf(float x) {
    unsigned int u = __float_as_uint(x);
    return (unsigned short)((u + 0x7fffu + ((u >> 16) & 1u)) >> 16);
}
static __device__ __forceinline__ float bf2f(unsigned short h) {
    return __uint_as_float(((unsigned int)h) << 16);
}

// async global->LDS, 16B per lane; lds base must be wave-uniform
static __device__ __forceinline__ void gload16(const unsigned short* g, unsigned short* l) {
    __builtin_amdgcn_global_load_lds(
        (const __attribute__((address_space(1))) unsigned int*)g,
        (__attribute__((address_space(3))) unsigned int*)l, 16, 0, 0);
}

// ---------------- K0: fp32 -> bf16 hi/lo split (flat) ----------------
__global__ __launch_bounds__(256) void conv_kernel(const float* __restrict__ src,
                                                   unsigned short* __restrict__ hi,
                                                   unsigned short* __restrict__ lo) {
    const int t = blockIdx.x * 256 + threadIdx.x;
    const int base = t * 8;
    const float4 v0 = *(const float4*)&src[base];
    const float4 v1 = *(const float4*)&src[base + 4];
    short8 h, l;
#pragma unroll
    for (int j = 0; j < 4; j++) {
        float x = ((const float*)&v0)[j];
        unsigned short hh = f2bf(x);
        h[j] = (short)hh;
        l[j] = (short)f2bf(x - bf2f(hh));
    }
#pragma unroll
    for (int j = 0; j < 4; j++) {
        float x = ((const float*)&v1)[j];
        unsigned short hh = f2bf(x);
        h[4 + j] = (short)hh;
        l[4 + j] = (short)f2bf(x - bf2f(hh));
    }
    *(short8*)&hi[base] = h;
    *(short8*)&lo[base] = l;
}

// ---------------- K1: embedding norms (exact fp32) ----------------
__global__ __launch_bounds__(256) void norms_kernel(const float* __restrict__ emb,
                                                    float* __restrict__ enorm) {
    const int k = blockIdx.x * 4 + (threadIdx.x >> 6);
    const int lane = threadIdx.x & 63;
    float4 v = *(const float4*)&emb[k * DDIM + lane * 4];
    float s = v.x * v.x + v.y * v.y + v.z * v.z + v.w * v.w;
    for (int o = 32; o; o >>= 1) s += __shfl_down(s, o);
    if (lane == 0) enorm[k] = s;
}

// ---------------- K2: init outputs + keys + scalars ----------------
__global__ __launch_bounds__(256) void init_kernel(const float* __restrict__ ecs_in,
                                                   const float* __restrict__ ees_in,
                                                   float* __restrict__ o_ecs,
                                                   float* __restrict__ o_ees,
                                                   unsigned long long* __restrict__ key64,
                                                   float* __restrict__ scal) {
    const int i = blockIdx.x * 256 + threadIdx.x;
    o_ees[i] = DECAYF * ees_in[i];
    if (i < KEMB) o_ecs[i] = DECAYF * ecs_in[i];
    if (i < NROWS) key64[i] = ~0ull;
    if (i < 2) scal[i] = 0.0f;
}

// ---------------- K3: bf16x3 MFMA distance GEMM + fused argmin ----------------
// Block: 128x128, 4 waves (2x2 of 64x64), BK=32, pre-split bf16 inputs,
// global_load_lds staging (no conversion VALU, no ds_writes).
__global__ __launch_bounds__(256) void argmin_mfma(const unsigned short* __restrict__ zh,
                                                   const unsigned short* __restrict__ zl,
                                                   const unsigned short* __restrict__ eh,
                                                   const unsigned short* __restrict__ el,
                                                   const float* __restrict__ enorm,
                                                   unsigned long long* __restrict__ key64) {
    __shared__ unsigned short Ah[128][32];   // pitch 64B: b128 frag reads bank-balanced
    __shared__ unsigned short Al[128][32];
    __shared__ unsigned short Bh[128][32];
    __shared__ unsigned short Bl[128][32];

    const int tid = threadIdx.x;
    const int lane = tid & 63;
    const int wid = tid >> 6;
    const int wm = wid >> 1, wn = wid & 1;
    const int tx = lane & 15, quad = lane >> 4;

    const int row0 = blockIdx.x * 128;
    const int col0 = blockIdx.y * 128;

    // staging: wave w covers rows [w*32, w*32+32) of both tiles;
    // lane l -> local row l>>2, 16B chunk l&3 (matches lds dst = base + lane*16)
    const int w32 = wid * 32;
    const int r16 = lane >> 2;
    const int c8 = (lane & 3) * 8;

    f32x4 acc[4][4];
#pragma unroll
    for (int i = 0; i < 4; i++)
#pragma unroll
        for (int j = 0; j < 4; j++) acc[i][j] = (f32x4){0.f, 0.f, 0.f, 0.f};

    for (int dstep = 0; dstep < DDIM; dstep += 32) {
        __syncthreads();   // all waves done reading previous tile
#pragma unroll
        for (int i = 0; i < 2; i++) {
            const int lr = w32 + i * 16;
            const long ga = (long)(row0 + lr + r16) * DDIM + dstep + c8;
            const long gb = (long)(col0 + lr + r16) * DDIM + dstep + c8;
            gload16(&zh[ga], &Ah[lr][0]);
            gload16(&zl[ga], &Al[lr][0]);
            gload16(&eh[gb], &Bh[lr][0]);
            gload16(&el[gb], &Bl[lr][0]);
        }
        __syncthreads();   // drains vmcnt: LDS tiles complete

        short8 aH[4], aL[4], bH[4], bL[4];
        const int ar = wm * 64 + tx;
        const int br = wn * 64 + tx;
#pragma unroll
        for (int mi = 0; mi < 4; mi++) {
            aH[mi] = *(const short8*)&Ah[ar + mi * 16][quad * 8];
            aL[mi] = *(const short8*)&Al[ar + mi * 16][quad * 8];
        }
#pragma unroll
        for (int nj = 0; nj < 4; nj++) {
            bH[nj] = *(const short8*)&Bh[br + nj * 16][quad * 8];
            bL[nj] = *(const short8*)&Bl[br + nj * 16][quad * 8];
        }
#pragma unroll
        for (int mi = 0; mi < 4; mi++)
#pragma unroll
            for (int nj = 0; nj < 4; nj++) {
                acc[mi][nj] = __builtin_amdgcn_mfma_f32_16x16x32_bf16(aH[mi], bH[nj], acc[mi][nj], 0, 0, 0);
                acc[mi][nj] = __builtin_amdgcn_mfma_f32_16x16x32_bf16(aL[mi], bH[nj], acc[mi][nj], 0, 0, 0);
                acc[mi][nj] = __builtin_amdgcn_mfma_f32_16x16x32_bf16(aH[mi], bL[nj], acc[mi][nj], 0, 0, 0);
            }
    }

    // epilogue: dist = ||e||^2 - 2 x.e ; fused argmin, k-ascending tie-break.
    // C/D layout: col = lane&15 (+nj*16), row = quad*4 + reg (+mi*16)
    float en[4];
    int colv[4];
#pragma unroll
    for (int nj = 0; nj < 4; nj++) {
        colv[nj] = col0 + wn * 64 + nj * 16 + tx;
        en[nj] = enorm[colv[nj]];
    }
#pragma unroll
    for (int mi = 0; mi < 4; mi++) {
#pragma unroll
        for (int r = 0; r < 4; r++) {
            unsigned long long best = ~0ull;
#pragma unroll
            for (int nj = 0; nj < 4; nj++) {
                float d = en[nj] - 2.0f * acc[mi][nj][r];
                unsigned int db = __float_as_uint(d);
                db = (db & 0x80000000u) ? ~db : (db | 0x80000000u);
                unsigned long long key = ((unsigned long long)db << 32) | (unsigned int)colv[nj];
                if (key < best) best = key;
            }
#pragma unroll
            for (int m = 1; m < 16; m <<= 1) {
                unsigned long long o = __shfl_xor(best, m);
                if (o < best) best = o;
            }
            if (tx == 0)
                atomicMin(&key64[row0 + wm * 64 + mi * 16 + quad * 4 + r], best);
        }
    }
}

// ---------------- K5: decode idx + quantize + commit-loss + EMA stats -------
__global__ __launch_bounds__(256) void quant_stats(const float* __restrict__ z,
                                                   const float* __restrict__ emb,
                                                   const unsigned long long* __restrict__ key64,
                                                   float* __restrict__ o_qst,
                                                   float* __restrict__ o_idx,
                                                   float* __restrict__ o_ecs,
                                                   float* __restrict__ o_ees,
                                                   float* __restrict__ scal) {
    const int n = (blockIdx.x * 256 + threadIdx.x) >> 6;   // one wave per row
    const int lane = threadIdx.x & 63;
    const int k = (int)(key64[n] & 0xFFFFFFFFull);
    const int d0 = lane * 4;
    const float4 zv = *(const float4*)&z[n * DDIM + d0];
    const float4 ev = *(const float4*)&emb[k * DDIM + d0];
    const float dx = ev.x - zv.x, dy = ev.y - zv.y, dz2 = ev.z - zv.z, dw = ev.w - zv.w;
    float4 q;
    q.x = zv.x + dx; q.y = zv.y + dy; q.z = zv.z + dz2; q.w = zv.w + dw;
    *(float4*)&o_qst[n * DDIM + d0] = q;
    float p = dx * dx + dy * dy + dz2 * dz2 + dw * dw;
    for (int o = 32; o; o >>= 1) p += __shfl_down(p, o);
    if (lane == 0) {
        o_idx[n] = (float)k;
        atomicAdd(&scal[0], p);
        atomicAdd(&o_ecs[k], ONE_MINUS_DECAY);
    }
    atomicAdd(&o_ees[k * DDIM + d0 + 0], ONE_MINUS_DECAY * zv.x);
    atomicAdd(&o_ees[k * DDIM + d0 + 1], ONE_MINUS_DECAY * zv.y);
    atomicAdd(&o_ees[k * DDIM + d0 + 2], ONE_MINUS_DECAY * zv.z);
    atomicAdd(&o_ees[k * DDIM + d0 + 3], ONE_MINUS_DECAY * zv.w);
}

// ---------------- K6a: n_tot = sum(new_ecs) ----------------
__global__ __launch_bounds__(256) void ntot_kernel(const float* __restrict__ o_ecs,
                                                   float* __restrict__ scal) {
    const int i = blockIdx.x * 256 + threadIdx.x;
    float v = o_ecs[i];
    for (int o = 32; o; o >>= 1) v += __shfl_down(v, o);
    __shared__ float s[4];
    if ((threadIdx.x & 63) == 0) s[threadIdx.x >> 6] = v;
    __syncthreads();
    if (threadIdx.x == 0) atomicAdd(&scal[1], s[0] + s[1] + s[2] + s[3]);
}

// ---------------- K6b: new_embedding + loss scalar ----------------
__global__ __launch_bounds__(256) void finalize_kernel(const float* __restrict__ o_ecs,
                                                       const float* __restrict__ o_ees,
                                                       const float* __restrict__ scal,
                                                       float* __restrict__ o_emb,
                                                       float* __restrict__ o_loss) {
    const int k = blockIdx.x;
    const int d = threadIdx.x;
    const float ntot = scal[1];
    const float ecs = o_ecs[k];
    const float sm = (ecs + EPSF) / (ntot + (float)KEMB * EPSF) * ntot;
    o_emb[k * DDIM + d] = o_ees[k * DDIM + d] / sm;
    if (k == 0 && d == 0) o_loss[0] = 0.25f * scal[0] / (float)(NROWS * DDIM);
}

extern "C" void kernel_launch(void* const* d_in, const int* in_sizes, int n_in,
                              void* d_out, int out_size, void* d_ws, size_t ws_size,
                              hipStream_t stream) {
    const float* z   = (const float*)d_in[0];
    const float* emb = (const float*)d_in[1];
    const float* ecs = (const float*)d_in[2];
    const float* ees = (const float*)d_in[3];

    float* out = (float*)d_out;
    float* ws  = (float*)d_ws;

    float* enorm = ws + WS_NORMS;
    unsigned long long* key64 = (unsigned long long*)(ws + WS_KEY);
    float* scal  = ws + WS_SCAL;

    // bf16 hi/lo scratch lives in output regions that are overwritten later:
    // z hi+lo (16 MB) in O_QST (16.77 MB); e hi+lo (8 MB) in O_EMB (8 MB exact)
    unsigned short* zh = (unsigned short*)(out + O_QST);
    unsigned short* zl = zh + NROWS * DDIM;
    unsigned short* ehp = (unsigned short*)(out + O_EMB);
    unsigned short* elp = ehp + KEMB * DDIM;

    norms_kernel<<<KEMB / 4, 256, 0, stream>>>(emb, enorm);
    init_kernel<<<(KEMB * DDIM) / 256, 256, 0, stream>>>(ecs, ees, out + O_ECS, out + O_EES, key64, scal);
    conv_kernel<<<(NROWS * DDIM) / 2048, 256, 0, stream>>>(z, zh, zl);
    conv_kernel<<<(KEMB * DDIM) / 2048, 256, 0, stream>>>(emb, ehp, elp);
    argmin_mfma<<<dim3(NROWS / 128, KEMB / 128), 256, 0, stream>>>(zh, zl, ehp, elp, enorm, key64);
    quant_stats<<<(NROWS * 64) / 256, 256, 0, stream>>>(z, emb, key64, out + O_QST, out + O_IDX,
                                                        out + O_ECS, out + O_EES, scal);
    ntot_kernel<<<KEMB / 256, 256, 0, stream>>>(out + O_ECS, scal);
    finalize_kernel<<<KEMB, DDIM, 0, stream>>>(out + O_ECS, out + O_EES, scal,
                                               out + O_EMB, out + O_LOSS);
}